// Round 19
// baseline (24.420 us; speedup 1.0000x reference)
//
#include <hip/hip_runtime.h>
#include <hip/hip_bf16.h>
#include <math.h>

#define D     128
#define NT    256            // B*T
#define HD    32
#define LD    32
#define P32   132            // u32-row pad for fp16-pair tiles
#define STW   136            // st row stride in u16 (272 B, 16B-aligned)
#define TILES 136            // 16*17/2 upper-incl-diag 8x8 tiles
#define NSLAB (TILES * 64)   // u16 per token in packed D

typedef _Float16 h2v __attribute__((ext_vector_type(2)));

static __device__ inline float bf2f(unsigned int u16v) {
    union { unsigned int i; float f; } v;
    v.i = u16v << 16;
    return v.f;
}
// fp16 pair pack via single v_cvt_pkrtz_f16_f32 (RTZ; error budget checked)
static __device__ inline unsigned int pkh2(float a, float b) {
    auto p = __builtin_amdgcn_cvt_pkrtz(a, b);
    union { decltype(p) h; unsigned int u; } cv;
    cv.h = p;
    return cv.u;
}
static __device__ inline h2v u2h(unsigned int u) {
    union { unsigned int u; h2v h; } cv; cv.u = u; return cv.h;
}
static __device__ inline float fdot2f(h2v a, h2v b, float c) {
#if __has_builtin(__builtin_amdgcn_fdot2)
    return __builtin_amdgcn_fdot2(a, b, c, false);
#else
    return c + (float)a[0] * (float)b[0] + (float)a[1] * (float)b[1];
#endif
}
// 2x f32 -> packed bf16 pair (RNE), single instruction on gfx950
static __device__ inline unsigned int cvtpk_bf16(float lo, float hi) {
    unsigned int r;
    asm("v_cvt_pk_bf16_f32 %0, %1, %2" : "=v"(r) : "v"(lo), "v"(hi));
    return r;
}

union SmemA {                        // staging (P1) overlaid with lin (P2+)
    struct {
        unsigned int zt[16][P32];    // fp16 l-pairs of z, transposed: 8.4 KB
        unsigned int w1pk[32][36];   // fp16 l-pairs of W1 rows: 4.6 KB
        unsigned int w2p[16];        // fp16 h-pairs of w2/2: 64 B
    } s;
    float lin[2][D];                 // rank-1 relu-split terms, 1 KB
};
union SmemB {                        // fp16-pair pa/pb overlaid with st buf
    struct { unsigned int a[16][P32]; unsigned int b[16][P32]; } p;  // 16.9 KB
    unsigned short st[D][STW];                                       // 34.8 KB
};

// ---------------------------------------------------------------------------
// K12: one block per token n, 512 threads. P3 at its ISA instruction floor
// (pk_add + and(|.|x2) + fdot2 = 3 VALU per 2h/cell). vs R18: pkrtz packs,
// epilogue address math hoisted above the final barrier.
// ---------------------------------------------------------------------------
__global__ __launch_bounds__(512) void fused_pab_scores(
    const float* __restrict__ z, const float* __restrict__ W1,
    const float* __restrict__ b1, const float* __restrict__ W2,
    unsigned short* __restrict__ Dp)
{
    __shared__ SmemA sa;
    __shared__ SmemB sb;

    const int t = threadIdx.x;
    const int n = blockIdx.x;

    // ---- stage z transposed as fp16 l-pairs: 1024 float4, 2/thread ----
    {
        const float4* zsrc = (const float4*)(z + (size_t)n * (D * LD));
        #pragma unroll
        for (int q = 0; q < 2; ++q) {
            int f = t + q * 512;
            float4 v = zsrc[f];
            int i  = f >> 3;             // 0..127
            int l2 = (f & 7) * 2;        // l-pair index
            sa.s.zt[l2][i]     = pkh2(v.x, v.y);
            sa.s.zt[l2 + 1][i] = pkh2(v.z, v.w);
        }
    }
    // ---- stage W1 packed cooperatively: 1024 u32, 2/thread ----
    {
        #pragma unroll
        for (int q = 0; q < 2; ++q) {
            int u = t + q * 512;         // 0..1023
            float2 w = *(const float2*)&W1[2 * u];
            sa.s.w1pk[u >> 5][u & 31] = pkh2(w.x, w.y);
        }
    }
    if (t < 16)
        sa.s.w2p[t] = pkh2(0.5f * W2[2 * t], 0.5f * W2[2 * t + 1]);

    const int h2i = t & 15;              // h-pair 0..15
    const int iq  = t >> 4;              // i-quad 0..31
    const int h0 = 2 * h2i, h1 = h0 + 1;
    const float bias0 = b1[h0], bias1 = b1[h1];
    __syncthreads();                     // (1) z/W1/w2 staged

    // ---- read back packed W1 rows + w2 (b128 batches) ----
    unsigned int wpkA0[16], wpkA1[16], wpkB0[16], wpkB1[16], w2pk[16];
    #pragma unroll
    for (int k = 0; k < 4; ++k) {
        *(uint4*)&wpkA0[4*k] = *(const uint4*)&sa.s.w1pk[h0][4*k];
        *(uint4*)&wpkB0[4*k] = *(const uint4*)&sa.s.w1pk[h0][16 + 4*k];
        *(uint4*)&wpkA1[4*k] = *(const uint4*)&sa.s.w1pk[h1][4*k];
        *(uint4*)&wpkB1[4*k] = *(const uint4*)&sa.s.w1pk[h1][16 + 4*k];
        *(uint4*)&w2pk[4*k]  = *(const uint4*)&sa.s.w2p[4*k];
    }

    // ---- P1: 4 i's x (h0,h1) x (a,b) = 16 f32 accs over 16 fdot2 ----
    {
        float A0[4], A1[4], B0[4], B1[4];
        #pragma unroll
        for (int r = 0; r < 4; ++r) { A0[r] = bias0; A1[r] = bias1; B0[r] = 0.f; B1[r] = 0.f; }
        #pragma unroll
        for (int l2 = 0; l2 < 16; ++l2) {
            unsigned int zq[4];
            *(uint4*)zq = *(const uint4*)&sa.s.zt[l2][iq * 4];
            #pragma unroll
            for (int r = 0; r < 4; ++r) {
                h2v zv = u2h(zq[r]);
                A0[r] = fdot2f(zv, u2h(wpkA0[l2]), A0[r]);
                A1[r] = fdot2f(zv, u2h(wpkA1[l2]), A1[r]);
                B0[r] = fdot2f(zv, u2h(wpkB0[l2]), B0[r]);
                B1[r] = fdot2f(zv, u2h(wpkB1[l2]), B1[r]);
            }
        }
        unsigned int pa4[4], pb4[4];
        #pragma unroll
        for (int r = 0; r < 4; ++r) {
            pa4[r] = pkh2(A0[r], A1[r]);     // pack across h-pair
            pb4[r] = pkh2(B0[r], B1[r]);
        }
        *(uint4*)&sb.p.a[h2i][iq * 4] = *(uint4*)pa4;
        *(uint4*)&sb.p.b[h2i][iq * 4] = *(uint4*)pb4;
    }
    __syncthreads();                     // (2) fp16 pa/pb ready; staging dead

    // ---- P2 (t<256; overlaps P3, joined at barrier (3)) ----
    if (t < 256) {
        const int kind = t >> 7, i2 = t & 127;
        float s = 0.f;
        #pragma unroll
        for (int q = 0; q < 16; ++q) {
            unsigned int v = kind ? sb.p.b[q][i2] : sb.p.a[q][i2];
            s = fdot2f(u2h(v), u2h(w2pk[q]), s);
        }
        sa.lin[kind][i2] = s;            // consumed after barrier (3)
    }

    // ---- P3: abs part, 8i x 4j per thread, fp16-pair datapath ----
    const int tx = t & 31;               // j-quad
    const int ty = t >> 5;               // i-oct
    float acc[8][4];
    #pragma unroll
    for (int r = 0; r < 8; ++r)
        #pragma unroll
        for (int c = 0; c < 4; ++c) acc[r][c] = 0.f;

    #pragma unroll 4
    for (int q = 0; q < 16; ++q) {
        unsigned int a8[8], b4[4];
        *(uint4*)&a8[0] = *(const uint4*)&sb.p.a[q][ty * 8];
        *(uint4*)&a8[4] = *(const uint4*)&sb.p.a[q][ty * 8 + 4];
        *(uint4*)&b4[0] = *(const uint4*)&sb.p.b[q][tx * 4];
        const h2v w = u2h(w2pk[q]);
        #pragma unroll
        for (int r = 0; r < 8; ++r) {
            const h2v ha = u2h(a8[r]);
            #pragma unroll
            for (int c = 0; c < 4; ++c) {
                union { h2v h; unsigned int u; } cv;
                cv.h = ha + u2h(b4[c]);              // v_pk_add_f16
                cv.u &= 0x7fff7fffu;                 // |.| both halves
                acc[r][c] = fdot2f(cv.h, w, acc[r][c]);
            }
        }
    }
    __syncthreads();                     // (3) P3/P2 reads done; lin visible

    // ---- add linear terms ----
    {
        float cai[8], cbj[4];
        #pragma unroll
        for (int r = 0; r < 8; ++r) cai[r] = sa.lin[0][ty * 8 + r];
        #pragma unroll
        for (int c = 0; c < 4; ++c) cbj[c] = sa.lin[1][tx * 4 + c];
        #pragma unroll
        for (int r = 0; r < 8; ++r)
            #pragma unroll
            for (int c = 0; c < 4; ++c)
                acc[r][c] += cai[r] + cbj[c];
    }

    // ---- hoisted epilogue address math (overlaps barrier wait) ----
    const int jo = tx >> 1;              // j-oct 0..15
    const int jh = tx & 1;               // half within oct
    const int physW = ((jo ^ (ty & 7)) * 8) + jh * 4;
    const int physR = (ty ^ (jo & 7)) * 8;
    const int tidx  = ty * 16 - (ty * (ty - 1)) / 2 + (jo - ty);
    unsigned short* const Dn = Dp + (size_t)n * NSLAB + tidx * 64 + jh * 4;

    // ---- S -> st (bf16 via cvt_pk, XOR oct-swizzled) ----
    #pragma unroll
    for (int r = 0; r < 8; ++r) {
        unsigned int p0 = cvtpk_bf16(acc[r][0], acc[r][1]);
        unsigned int p1 = cvtpk_bf16(acc[r][2], acc[r][3]);
        *(uint2*)&sb.st[ty * 8 + r][physW] = make_uint2(p0, p1);
    }
    __syncthreads();                     // (4) S complete

    // ---- upper-tri tiles only: D = acc - S^T, packed write ----
    if (jo >= ty) {
        float sji[4][8];                 // sji[c][r] = S[j][i=ty*8+r]
        #pragma unroll
        for (int c = 0; c < 4; ++c) {
            const int j = jo * 8 + jh * 4 + c;
            uint4 u = *(const uint4*)&sb.st[j][physR];
            unsigned int xs[4] = {u.x, u.y, u.z, u.w};
            #pragma unroll
            for (int k = 0; k < 4; ++k) {
                sji[c][2*k]   = bf2f(xs[k] & 0xffff);
                sji[c][2*k+1] = bf2f(xs[k] >> 16);
            }
        }
        #pragma unroll
        for (int r = 0; r < 8; ++r) {
            unsigned int p0 = cvtpk_bf16(acc[r][0] - sji[0][r],
                                         acc[r][1] - sji[1][r]);
            unsigned int p1 = cvtpk_bf16(acc[r][2] - sji[2][r],
                                         acc[r][3] - sji[3][r]);
            *(uint2*)&Dn[r * 8] = make_uint2(p0, p1);
        }
    }
}

// ---------------------------------------------------------------------------
// K3: one block per packed tile, 1024 threads: 2 uint4 loads per thread
// (min serial load depth), 3-stage LDS reduce (128 -> 16 -> 1).
// ---------------------------------------------------------------------------
__global__ __launch_bounds__(1024) void finalize_tiles(
    const unsigned short* __restrict__ Dp, const float* __restrict__ Wmag,
    float* __restrict__ out)
{
    __shared__ float red[128][72];       // 128 n-groups x 64 cells, 36.9 KB
    __shared__ float red2[16][72];       // second stage, 4.6 KB

    const int b = blockIdx.x;            // 0..135
    int tq = 0, base = 0;                // invert b -> (tq, tp), uniform scalar
    while (b >= base + (16 - tq)) { base += 16 - tq; ++tq; }
    const int tp = tq + (b - base);

    const int t = threadIdx.x;
    const int g = t >> 3;                // n-group 0..127 (2 n each)
    const int s = t & 7;                 // tile row

    float a8[8] = {0.f, 0.f, 0.f, 0.f, 0.f, 0.f, 0.f, 0.f};
    #pragma unroll
    for (int q = 0; q < 2; ++q) {
        const int nn = g * 2 + q;
        uint4 u = *(const uint4*)&Dp[(size_t)nn * NSLAB + b * 64 + s * 8];
        unsigned int xs[4] = {u.x, u.y, u.z, u.w};
        #pragma unroll
        for (int k = 0; k < 4; ++k) {
            a8[2*k]   += bf2f(xs[k] & 0xffff);
            a8[2*k+1] += bf2f(xs[k] >> 16);
        }
    }
    *(float4*)&red[g][s * 8]     = make_float4(a8[0], a8[1], a8[2], a8[3]);
    *(float4*)&red[g][s * 8 + 4] = make_float4(a8[4], a8[5], a8[6], a8[7]);
    __syncthreads();

    // stage 2: 1024 threads: cell (t&63), 8-group slice (t>>6 = 0..15)
    {
        const int cell = t & 63, sl = t >> 6;
        float s2 = 0.f;
        #pragma unroll
        for (int k = 0; k < 8; ++k) s2 += red[sl * 8 + k][cell];
        red2[sl][cell] = s2;
    }
    __syncthreads();

    if (t < 64) {
        const int r = t >> 3, c = t & 7;
        float sum = 0.f;
        #pragma unroll
        for (int k = 0; k < 16; ++k) sum += red2[k][t];

        const int i = 8 * tq + r;
        const int j = 8 * tp + c;
        if (i == j) {                    // diag cell: owned once (tq==tp, r==c)
            out[i * D + i]         = 0.f;
            out[D * D + i * D + i] = 0.f;
        } else if (j > i) {              // valid cell (all cells if tp>tq)
            float av  = sum * (1.0f / 256.0f);        // mean over n; TAU = 1
            float dir = 1.0f / (1.0f + __expf(-av));
            float wmm = 0.5f * (Wmag[i * D + j] + Wmag[j * D + i]);
            float sw  = 1.0f / (1.0f + __expf(-wmm));
            out[i * D + j]         = dir * sw;          // A[i][j]
            out[j * D + i]         = (1.0f - dir) * sw; // A[j][i] = sigma(-av)*sw
            out[D * D + i * D + j] = wmm;
            out[D * D + j * D + i] = wmm;
        }
        // cells j < i in diag tiles: mirrored by their (c,r) counterpart
    }
}

extern "C" void kernel_launch(void* const* d_in, const int* in_sizes, int n_in,
                              void* d_out, int out_size, void* d_ws, size_t ws_size,
                              hipStream_t stream)
{
    const float* z    = (const float*)d_in[0];   // (4,64,128,32)
    const float* Wmag = (const float*)d_in[1];   // (128,128)
    const float* W1   = (const float*)d_in[2];   // (32,64)
    const float* b1   = (const float*)d_in[3];   // (32,)
    const float* W2   = (const float*)d_in[4];   // (1,32)
    // d_in[5] = b2: cancels in scores - scores^T.

    unsigned short* Dp = (unsigned short*)d_ws;  // packed upper-tri D, 4.35 MB
    float* out = (float*)d_out;

    fused_pab_scores<<<NT, 512, 0, stream>>>(z, W1, b1, W2, Dp);
    finalize_tiles<<<TILES, 1024, 0, stream>>>(Dp, Wmag, out);
}